// Round 1
// baseline (56.075 us; speedup 1.0000x reference)
//
#include <hip/hip_runtime.h>

namespace {

constexpr int NDIM = 32;   // input dim (columns of x)
constexpr int HDIM = 64;   // hidden
constexpr int ODIM = 32;   // output / phi out
constexpr float PAIRS = 496.0f;  // 32*31/2

// ws layout: float2 M2[64][64]  (M2[hp][h] = {Ma[h][hp], Mb[h][hp]}), then float cconst[64]
// Ma = psi_w1[:, :O] @ phi_w2   (HxH),  Mb = psi_w1[:, O:] @ phi_w2
// cconst[h] = psi_b1[h] + sum_o (psi_w1[h,o] + psi_w1[h,O+o]) * phi_b2[o]
__global__ __launch_bounds__(64) void kan_precompute(
    const float* __restrict__ phi_w2, const float* __restrict__ phi_b2,
    const float* __restrict__ psi_w1, const float* __restrict__ psi_b1,
    float2* __restrict__ M2, float* __restrict__ cconst)
{
    const int h  = blockIdx.x;    // 0..63  (row of Ma/Mb)
    const int hp = threadIdx.x;   // 0..63  (col of Ma/Mb)
    float ma = 0.f, mb = 0.f;
#pragma unroll
    for (int o = 0; o < ODIM; ++o) {
        const float pw = phi_w2[o * HDIM + hp];
        ma = fmaf(psi_w1[h * 2 * ODIM + o],        pw, ma);
        mb = fmaf(psi_w1[h * 2 * ODIM + ODIM + o], pw, mb);
    }
    M2[hp * HDIM + h] = make_float2(ma, mb);   // stored transposed for lane-major reads
    if (hp == 0) {
        float c = psi_b1[h];
#pragma unroll
        for (int o = 0; o < ODIM; ++o)
            c = fmaf(psi_w1[h * 2 * ODIM + o] + psi_w1[h * 2 * ODIM + ODIM + o],
                     phi_b2[o], c);
        cconst[h] = c;
    }
}

// One wave (64 lanes) per batch element; lane = hidden channel h.
__global__ __launch_bounds__(256, 2) void kan_main(
    const float* __restrict__ x, const float* __restrict__ phi_w1,
    const float* __restrict__ phi_b1, const float* __restrict__ psi_w2,
    const float* __restrict__ psi_b2, const float2* __restrict__ M2,
    const float* __restrict__ cconst, float* __restrict__ out)
{
    __shared__ float2 M2s[HDIM * HDIM];      // 32 KB  [hp][h]
    __shared__ float  w2Ts[HDIM * ODIM];     //  8 KB  [h][o] = psi_w2[o][h]
    __shared__ float  h1s[4][NDIM][HDIM];    // 32 KB  per-wave h1 tiles
    __shared__ float  xs[4][NDIM];           // per-wave x row
    __shared__ float  sred[4][HDIM];         // per-wave S for epilogue

    const int tid  = threadIdx.x;
    const int wave = tid >> 6;
    const int lane = tid & 63;

    // ---- cooperative staging -------------------------------------------
    {
        const float4* src = (const float4*)M2;   // 2048 float4
        float4* dst = (float4*)M2s;
#pragma unroll
        for (int k = 0; k < 8; ++k)
            dst[tid + 256 * k] = src[tid + 256 * k];
#pragma unroll
        for (int k = 0; k < 8; ++k) {            // transpose psi_w2 into LDS
            const int idx = tid + 256 * k;       // idx = h*32 + o
            const int hh = idx >> 5, oo = idx & 31;
            w2Ts[idx] = psi_w2[oo * HDIM + hh];
        }
        if (tid < 4 * NDIM) {
            const int wv = tid >> 5, n = tid & 31;
            xs[wv][n] = x[(blockIdx.x * 4 + wv) * NDIM + n];
        }
    }
    __syncthreads();

    const float w1h = phi_w1[lane];
    const float b1h = phi_b1[lane];
    const float cch = cconst[lane];

    // ---- stage 1: h1[n][h] = relu(x[n]*w1[h] + b1[h]) ------------------
#pragma unroll
    for (int n = 0; n < NDIM; ++n)
        h1s[wave][n][lane] = fmaxf(fmaf(xs[wave][n], w1h, b1h), 0.f);
    __syncthreads();

    // ---- stage 2: A[n] = cconst[h] + (Ma h1_n)[h], Bv[n] = (Mb h1_n)[h]
    float A[NDIM], Bv[NDIM];
#pragma unroll
    for (int n = 0; n < NDIM; ++n) { A[n] = cch; Bv[n] = 0.f; }

    for (int q = 0; q < 16; ++q) {       // 4 h' per iteration
        const float2 m0 = M2s[(q * 4 + 0) * HDIM + lane];
        const float2 m1 = M2s[(q * 4 + 1) * HDIM + lane];
        const float2 m2 = M2s[(q * 4 + 2) * HDIM + lane];
        const float2 m3 = M2s[(q * 4 + 3) * HDIM + lane];
#pragma unroll
        for (int n = 0; n < NDIM; ++n) {
            const float4 hv = *(const float4*)&h1s[wave][n][q * 4]; // broadcast b128
            A[n]  = fmaf(hv.x, m0.x, A[n]);
            A[n]  = fmaf(hv.y, m1.x, A[n]);
            A[n]  = fmaf(hv.z, m2.x, A[n]);
            A[n]  = fmaf(hv.w, m3.x, A[n]);
            Bv[n] = fmaf(hv.x, m0.y, Bv[n]);
            Bv[n] = fmaf(hv.y, m1.y, Bv[n]);
            Bv[n] = fmaf(hv.z, m2.y, Bv[n]);
            Bv[n] = fmaf(hv.w, m3.y, Bv[n]);
        }
    }

    // ---- stage 3: S[h] = sum_{i<j} relu(A[i] + Bv[j]) ------------------
    float S = 0.f;
#pragma unroll
    for (int i = 0; i < NDIM - 1; ++i) {
#pragma unroll
        for (int j = i + 1; j < NDIM; ++j)
            S += fmaxf(A[i] + Bv[j], 0.f);
    }

    sred[wave][lane] = S;
    __syncthreads();

    // ---- epilogue: out[o] = psi_w2[o,:] . S + P*psi_b2[o] --------------
    const int oo   = lane & 31;
    const int half = lane >> 5;
    float part = 0.f;
#pragma unroll
    for (int k = 0; k < 32; ++k) {
        const int hh = half * 32 + k;
        part = fmaf(w2Ts[hh * ODIM + oo], sred[wave][hh], part);
    }
    part += __shfl_down(part, 32);
    if (half == 0) {
        const int batch = blockIdx.x * 4 + wave;
        out[batch * ODIM + oo] = part + PAIRS * psi_b2[oo];
    }
}

} // namespace

extern "C" void kernel_launch(void* const* d_in, const int* in_sizes, int n_in,
                              void* d_out, int out_size, void* d_ws, size_t ws_size,
                              hipStream_t stream)
{
    const float* x      = (const float*)d_in[0];
    const float* phi_w1 = (const float*)d_in[1];
    const float* phi_b1 = (const float*)d_in[2];
    const float* phi_w2 = (const float*)d_in[3];
    const float* phi_b2 = (const float*)d_in[4];
    const float* psi_w1 = (const float*)d_in[5];
    const float* psi_b1 = (const float*)d_in[6];
    const float* psi_w2 = (const float*)d_in[7];
    const float* psi_b2 = (const float*)d_in[8];

    float2* M2    = (float2*)d_ws;
    float* cconst = (float*)d_ws + 2 * 64 * 64;
    float* out    = (float*)d_out;

    kan_precompute<<<64, 64, 0, stream>>>(phi_w2, phi_b2, psi_w1, psi_b1, M2, cconst);
    kan_main<<<4096 / 4, 256, 0, stream>>>(x, phi_w1, phi_b1, psi_w2, psi_b2,
                                           M2, cconst, out);
}

// Round 2
// 43.712 us; speedup vs baseline: 1.2828x; 1.2828x over previous
//
#include <hip/hip_runtime.h>

namespace {

typedef float v2f __attribute__((ext_vector_type(2)));
typedef float v4f __attribute__((ext_vector_type(4)));

constexpr int NDIM = 32;   // input dim
constexpr int HDIM = 64;   // hidden
constexpr int ODIM = 32;   // output
constexpr float PAIRS = 496.0f;  // 32*31/2

// ---- packed fp32 helpers (VOP3P v_pk_fma_f32 with op_sel splat) ----------
// d.x += s.x*m.x ; d.y += s.x*m.y      (splat LOW half of s into both ops)
__device__ inline void pk_fma_lo(v2f& d, v2f s, v2f m) {
    asm("v_pk_fma_f32 %0, %1, %2, %0 op_sel:[0,0,0] op_sel_hi:[0,1,1]"
        : "+v"(d) : "v"(s), "v"(m));
}
// d.x += s.y*m.x ; d.y += s.y*m.y      (splat HIGH half of s)
__device__ inline void pk_fma_hi(v2f& d, v2f s, v2f m) {
    asm("v_pk_fma_f32 %0, %1, %2, %0 op_sel:[1,0,0] op_sel_hi:[1,1,1]"
        : "+v"(d) : "v"(s), "v"(m));
}

// ws layout: float Mg[17][512]  (rows q=0..16; row 16 is never-used prefetch pad)
//   Mg[q][lane*8 + (k&3)*2 + {0,1}] = {Ma[lane][k], Mb[lane][k]},  k = q*4 + (k&3)
// then float cconst[64] at Mg + 17*512.
// Ma = psi_w1[:, :O] @ phi_w2 ; Mb = psi_w1[:, O:] @ phi_w2
// cconst[h] = psi_b1[h] + sum_o (psi_w1[h,o]+psi_w1[h,O+o]) * phi_b2[o]
__global__ __launch_bounds__(64) void kan_precompute(
    const float* __restrict__ phi_w2, const float* __restrict__ phi_b2,
    const float* __restrict__ psi_w1, const float* __restrict__ psi_b1,
    float* __restrict__ Mg, float* __restrict__ cconst)
{
    const int k = blockIdx.x;     // 0..63  (h' index)
    const int h = threadIdx.x;    // 0..63  (psi hidden row)
    float ma = 0.f, mb = 0.f;
#pragma unroll
    for (int o = 0; o < ODIM; ++o) {
        const float pw = phi_w2[o * HDIM + k];
        ma = fmaf(psi_w1[h * 2 * ODIM + o],        pw, ma);
        mb = fmaf(psi_w1[h * 2 * ODIM + ODIM + o], pw, mb);
    }
    float* dst = Mg + (size_t)(k >> 2) * 512 + h * 8 + (k & 3) * 2;
    dst[0] = ma;
    dst[1] = mb;
    if (k == 0) {
        float c = psi_b1[h];
#pragma unroll
        for (int o = 0; o < ODIM; ++o)
            c = fmaf(psi_w1[h * 2 * ODIM + o] + psi_w1[h * 2 * ODIM + ODIM + o],
                     phi_b2[o], c);
        cconst[h] = c;
    }
}

// One wave = one batch element. lane = hidden channel h.
__global__ __launch_bounds__(64, 4) void kan_main(
    const float* __restrict__ x, const float* __restrict__ phi_w1,
    const float* __restrict__ phi_b1, const float* __restrict__ psi_w2,
    const float* __restrict__ psi_b2, const float* __restrict__ Mg,
    const float* __restrict__ cconst, float* __restrict__ out)
{
    __shared__ float h1s[NDIM][HDIM];   // 8 KB, wave-private
    __shared__ float sred[HDIM];        // 256 B

    const int lane  = threadIdx.x;
    const int batch = blockIdx.x;

    const float w1h = phi_w1[lane];
    const float b1h = phi_b1[lane];
    const float cch = cconst[lane];

    // ---- stage 1: h1[n][lane] = relu(x[n]*w1 + b1) ---------------------
    const float* xrow = x + (size_t)batch * NDIM;
    v4f xv[8];
#pragma unroll
    for (int r = 0; r < 8; ++r) xv[r] = *(const v4f*)(xrow + 4 * r);
#pragma unroll
    for (int r = 0; r < 8; ++r)
#pragma unroll
        for (int e = 0; e < 4; ++e)
            h1s[4 * r + e][lane] = fmaxf(fmaf(xv[r][e], w1h, b1h), 0.f);
    __syncthreads();

    // ---- stage 2: ABp[n] = {cconst + (Ma h1_n)[lane], (Mb h1_n)[lane]} -
    v2f ABp[NDIM];
#pragma unroll
    for (int n = 0; n < NDIM; ++n) ABp[n] = (v2f){cch, 0.f};

    const float* mg = Mg + (size_t)lane * 8;
    v4f m0 = *(const v4f*)(mg);
    v4f m1 = *(const v4f*)(mg + 4);

    for (int qq = 0; qq < 8; ++qq) {             // q = 2*qq, 2*qq+1
        const float* mgq = mg + (size_t)qq * 1024;
        v4f a0 = *(const v4f*)(mgq + 512);       // prefetch q+1
        v4f a1 = *(const v4f*)(mgq + 516);
        const char* hb = (const char*)h1s + qq * 32;
#pragma unroll
        for (int n = 0; n < NDIM; ++n) {
            const v4f hv = *(const v4f*)(hb + n * 256);
            const v2f lo = __builtin_shufflevector(hv, hv, 0, 1);
            const v2f hi = __builtin_shufflevector(hv, hv, 2, 3);
            pk_fma_lo(ABp[n], lo, __builtin_shufflevector(m0, m0, 0, 1));
            pk_fma_hi(ABp[n], lo, __builtin_shufflevector(m0, m0, 2, 3));
            pk_fma_lo(ABp[n], hi, __builtin_shufflevector(m1, m1, 0, 1));
            pk_fma_hi(ABp[n], hi, __builtin_shufflevector(m1, m1, 2, 3));
        }
        v4f b0 = *(const v4f*)(mgq + 1024);      // prefetch q+2 (row 16 = pad)
        v4f b1 = *(const v4f*)(mgq + 1028);
#pragma unroll
        for (int n = 0; n < NDIM; ++n) {
            const v4f hv = *(const v4f*)(hb + 16 + n * 256);
            const v2f lo = __builtin_shufflevector(hv, hv, 0, 1);
            const v2f hi = __builtin_shufflevector(hv, hv, 2, 3);
            pk_fma_lo(ABp[n], lo, __builtin_shufflevector(a0, a0, 0, 1));
            pk_fma_hi(ABp[n], lo, __builtin_shufflevector(a0, a0, 2, 3));
            pk_fma_lo(ABp[n], hi, __builtin_shufflevector(a1, a1, 0, 1));
            pk_fma_hi(ABp[n], hi, __builtin_shufflevector(a1, a1, 2, 3));
        }
        m0 = b0; m1 = b1;
    }

    // ---- stage 3: S = sum_{i<j} relu(A[i] + Bv[j]) ---------------------
    float acc[4] = {0.f, 0.f, 0.f, 0.f};
#pragma unroll
    for (int i = 0; i < NDIM - 1; ++i)
#pragma unroll
        for (int j = i + 1; j < NDIM; ++j)
            acc[j & 3] += fmaxf(ABp[i].x + ABp[j].y, 0.f);
    const float S = (acc[0] + acc[1]) + (acc[2] + acc[3]);

    sred[lane] = S;
    __syncthreads();

    // ---- epilogue: out[o] = psi_w2[o,:] . S + P*psi_b2[o] --------------
    const int oo   = lane & 31;
    const int half = lane >> 5;
    const float* w2r = psi_w2 + oo * HDIM + half * 32;
    float part = 0.f;
#pragma unroll
    for (int r = 0; r < 8; ++r) {
        const v4f w = *(const v4f*)(w2r + 4 * r);
        const float* sr = &sred[half * 32 + 4 * r];
        part = fmaf(w[0], sr[0], part);
        part = fmaf(w[1], sr[1], part);
        part = fmaf(w[2], sr[2], part);
        part = fmaf(w[3], sr[3], part);
    }
    part += __shfl_down(part, 32);
    if (half == 0)
        out[(size_t)batch * ODIM + oo] = part + PAIRS * psi_b2[oo];
}

} // namespace

extern "C" void kernel_launch(void* const* d_in, const int* in_sizes, int n_in,
                              void* d_out, int out_size, void* d_ws, size_t ws_size,
                              hipStream_t stream)
{
    const float* x      = (const float*)d_in[0];
    const float* phi_w1 = (const float*)d_in[1];
    const float* phi_b1 = (const float*)d_in[2];
    const float* phi_w2 = (const float*)d_in[3];
    const float* phi_b2 = (const float*)d_in[4];
    const float* psi_w1 = (const float*)d_in[5];
    const float* psi_b1 = (const float*)d_in[6];
    const float* psi_w2 = (const float*)d_in[7];
    const float* psi_b2 = (const float*)d_in[8];

    float* Mg     = (float*)d_ws;          // 17*512 floats (row 16 = prefetch pad)
    float* cconst = Mg + 17 * 512;
    float* out    = (float*)d_out;

    kan_precompute<<<64, 64, 0, stream>>>(phi_w2, phi_b2, psi_w1, psi_b1, Mg, cconst);
    kan_main<<<4096, 64, 0, stream>>>(x, phi_w1, phi_b1, psi_w2, psi_b2,
                                      Mg, cconst, out);
}

// Round 3
// 23.117 us; speedup vs baseline: 2.4258x; 1.8909x over previous
//
#include <hip/hip_runtime.h>

namespace {

typedef float v2f  __attribute__((ext_vector_type(2)));
typedef float v4f  __attribute__((ext_vector_type(4)));
typedef float f32x16 __attribute__((ext_vector_type(16)));
typedef short bf16x8 __attribute__((ext_vector_type(8)));
typedef unsigned short ushort;
typedef unsigned short us8 __attribute__((ext_vector_type(8)));

constexpr int NDIM = 32;
constexpr int HDIM = 64;
constexpr int ODIM = 32;
constexpr float PAIRS = 496.0f;

// float -> bf16 bits, round-to-nearest-even
__device__ __forceinline__ ushort f2bf(float f) {
    unsigned int u = __builtin_bit_cast(unsigned int, f);
    u += 0x7fffu + ((u >> 16) & 1u);
    return (ushort)(u >> 16);
}

// ---------------------------------------------------------------------------
// Precompute: W[k][hh] (hh 0..63 = Ma-part, 64..127 = Mb-part) emitted
// directly in mfma_f32_32x32x16_bf16 B-fragment layout:
//   Bfrag[(s*4+c)*64 + lane][e]  =  bf16( W[16s + 8*(lane>>5) + e][32c + (lane&31)] )
// where W[k][h] = sum_o psi_w1[h, o]        * phi_w2[o, k]   (hh < 64)
//       W[k][64+h] = sum_o psi_w1[h, 32+o]  * phi_w2[o, k]
// cconst[h] = psi_b1[h] + sum_o (psi_w1[h,o] + psi_w1[h,32+o]) * phi_b2[o]
// ---------------------------------------------------------------------------
__global__ __launch_bounds__(64) void kan_precompute(
    const float* __restrict__ phi_w2, const float* __restrict__ phi_b2,
    const float* __restrict__ psi_w1, const float* __restrict__ psi_b1,
    ushort* __restrict__ Bfrag, float* __restrict__ cconst)
{
    const int s = blockIdx.x >> 2, c = blockIdx.x & 3;
    const int lane = threadIdx.x;
    const int row = lane & 31, half = lane >> 5;
    const int hh = 32 * c + row;
    const int h = hh & 63;
    const int off = (hh >= 64) ? ODIM : 0;

    us8 out8;
#pragma unroll
    for (int e = 0; e < 8; ++e) {
        const int k = 16 * s + 8 * half + e;
        float m = 0.f;
#pragma unroll
        for (int o = 0; o < ODIM; ++o)
            m = fmaf(psi_w1[h * 2 * ODIM + off + o], phi_w2[o * HDIM + k], m);
        out8[e] = f2bf(m);
    }
    *(us8*)(Bfrag + (size_t)(blockIdx.x * 64 + lane) * 8) = out8;

    if (blockIdx.x == 0) {
        float cch = psi_b1[lane];
#pragma unroll
        for (int o = 0; o < ODIM; ++o)
            cch = fmaf(psi_w1[lane * 2 * ODIM + o] + psi_w1[lane * 2 * ODIM + ODIM + o],
                       phi_b2[o], cch);
        cconst[lane] = cch;
    }
}

// ---------------------------------------------------------------------------
// Main: one wave per batch element, 4 waves per block (no barriers needed).
// ---------------------------------------------------------------------------
__global__ __launch_bounds__(256, 4) void kan_main(
    const float* __restrict__ x, const float* __restrict__ phi_w1,
    const float* __restrict__ phi_b1, const float* __restrict__ psi_w2,
    const float* __restrict__ psi_b2, const ushort* __restrict__ Bfrag,
    const float* __restrict__ cconst, float* __restrict__ out)
{
    __shared__ float sred[4][HDIM];   // 1 KB, wave-private slices

    const int tid  = threadIdx.x;
    const int wave = tid >> 6;
    const int lane = tid & 63;
    const int batch = blockIdx.x * 4 + wave;
    const int row  = lane & 31;
    const int half = lane >> 5;
    const bool hi  = lane >= 32;

    // ---- stage 1: h1 directly in A-fragment layout ---------------------
    // A-frag (32x32x16 bf16): lane holds A[row = lane&31][k = 16s + 8*(lane>>5) + e]
    const float xn = x[(size_t)batch * NDIM + row];
    bf16x8 afrag[4];
#pragma unroll
    for (int s = 0; s < 4; ++s) {
        const int kb = 16 * s + 8 * half;
        const v4f w1a = *(const v4f*)(phi_w1 + kb);
        const v4f w1b = *(const v4f*)(phi_w1 + kb + 4);
        const v4f b1a = *(const v4f*)(phi_b1 + kb);
        const v4f b1b = *(const v4f*)(phi_b1 + kb + 4);
        bf16x8 t;
#pragma unroll
        for (int e = 0; e < 4; ++e)
            t[e] = (short)f2bf(fmaxf(fmaf(xn, w1a[e], b1a[e]), 0.f));
#pragma unroll
        for (int e = 0; e < 4; ++e)
            t[4 + e] = (short)f2bf(fmaxf(fmaf(xn, w1b[e], b1b[e]), 0.f));
        afrag[s] = t;
    }

    // ---- stage 2: C = H1 @ W via MFMA, cconst folded into C-init -------
    const float cc0 = cconst[row];
    const float cc1 = cconst[32 + row];
    f32x16 acc0, acc1, acc2, acc3;
#pragma unroll
    for (int r = 0; r < 16; ++r) { acc0[r] = cc0; acc1[r] = cc1; acc2[r] = 0.f; acc3[r] = 0.f; }

    const bf16x8* Bf = (const bf16x8*)Bfrag;
#pragma unroll
    for (int s = 0; s < 4; ++s) {
        const bf16x8 b0 = Bf[(s * 4 + 0) * 64 + lane];
        const bf16x8 b1 = Bf[(s * 4 + 1) * 64 + lane];
        const bf16x8 b2 = Bf[(s * 4 + 2) * 64 + lane];
        const bf16x8 b3 = Bf[(s * 4 + 3) * 64 + lane];
        acc0 = __builtin_amdgcn_mfma_f32_32x32x16_bf16(afrag[s], b0, acc0, 0, 0, 0);
        acc1 = __builtin_amdgcn_mfma_f32_32x32x16_bf16(afrag[s], b1, acc1, 0, 0, 0);
        acc2 = __builtin_amdgcn_mfma_f32_32x32x16_bf16(afrag[s], b2, acc2, 0, 0, 0);
        acc3 = __builtin_amdgcn_mfma_f32_32x32x16_bf16(afrag[s], b3, acc3, 0, 0, 0);
    }

    // ---- redistribute: lane ends with full A[0..31], B[0..31] for h = lane
    // C-layout: col = lane&31, row(n) = (reg&3) + 8*(reg>>2) + 4*(lane>>5).
    // own tile: (hi ? acc1/acc3 : acc0/acc2); send the opposite tile to lane^32.
    v2f Ap0[8], Ap1[8], Bp0[8], Bp1[8];   // delta-0 and delta-4 n-halves, as n-pairs
#pragma unroll
    for (int q = 0; q < 8; ++q) {
        v2f own, snd, oth;
        own.x = hi ? acc1[2 * q]     : acc0[2 * q];
        own.y = hi ? acc1[2 * q + 1] : acc0[2 * q + 1];
        snd.x = hi ? acc0[2 * q]     : acc1[2 * q];
        snd.y = hi ? acc0[2 * q + 1] : acc1[2 * q + 1];
        oth.x = __shfl_xor(snd.x, 32);
        oth.y = __shfl_xor(snd.y, 32);
        Ap0[q].x = hi ? oth.x : own.x;  Ap0[q].y = hi ? oth.y : own.y;
        Ap1[q].x = hi ? own.x : oth.x;  Ap1[q].y = hi ? own.y : oth.y;
    }
#pragma unroll
    for (int q = 0; q < 8; ++q) {
        v2f own, snd, oth;
        own.x = hi ? acc3[2 * q]     : acc2[2 * q];
        own.y = hi ? acc3[2 * q + 1] : acc2[2 * q + 1];
        snd.x = hi ? acc2[2 * q]     : acc3[2 * q];
        snd.y = hi ? acc2[2 * q + 1] : acc3[2 * q + 1];
        oth.x = __shfl_xor(snd.x, 32);
        oth.y = __shfl_xor(snd.y, 32);
        Bp0[q].x = hi ? oth.x : own.x;  Bp0[q].y = hi ? oth.y : own.y;
        Bp1[q].x = hi ? own.x : oth.x;  Bp1[q].y = hi ? own.y : oth.y;
    }

    // n = 8g + 4w + r  ->  (w ? Xp1 : Xp0)[g*2 + (r>>1)], component (r&1)
    auto AF = [&](int n) -> float {
        const v2f p = ((n >> 2) & 1) ? Ap1[(n >> 3) * 2 + ((n & 3) >> 1)]
                                     : Ap0[(n >> 3) * 2 + ((n & 3) >> 1)];
        return (n & 1) ? p.y : p.x;
    };
    auto BPair = [&](int p) -> v2f {   // {B[2p], B[2p+1]}
        return ((p >> 1) & 1) ? Bp1[(p >> 2) * 2 + (p & 1)]
                              : Bp0[(p >> 2) * 2 + (p & 1)];
    };
    auto BFs = [&](int n) -> float {
        const v2f p = BPair(n >> 1);
        return (n & 1) ? p.y : p.x;
    };

    // ---- stage 3: S = sum_{i<j} relu(A[i] + B[j]) ----------------------
    v2f vacc0 = {0.f, 0.f}, vacc1 = {0.f, 0.f};
    float sacc = 0.f;
#pragma unroll
    for (int i = 0; i < NDIM - 1; ++i) {
        const float ai = AF(i);
        int j = i + 1;
        if (j & 1) { sacc += fmaxf(ai + BFs(j), 0.f); ++j; }
        const v2f ai2 = {ai, ai};
#pragma unroll
        for (int p = j >> 1; p < 16; ++p) {
            const v2f t = ai2 + BPair(p);
            v2f m;
            m.x = fmaxf(t.x, 0.f);
            m.y = fmaxf(t.y, 0.f);
            if (p & 1) vacc1 += m; else vacc0 += m;
        }
    }
    const float S = sacc + (vacc0.x + vacc0.y) + (vacc1.x + vacc1.y);

    sred[wave][lane] = S;   // same-wave producer/consumer: no barrier needed
    __builtin_amdgcn_s_waitcnt(0);  // lgkmcnt drain (compiler also inserts)

    // ---- epilogue: out[o] = psi_w2[o,:] . S + PAIRS * psi_b2[o] --------
    const int oo = row;
    const float* w2r = psi_w2 + (size_t)oo * HDIM + half * 32;
    float part = 0.f;
#pragma unroll
    for (int r = 0; r < 8; ++r) {
        const v4f w = *(const v4f*)(w2r + 4 * r);
        const float* sr = &sred[wave][half * 32 + 4 * r];
        part = fmaf(w[0], sr[0], part);
        part = fmaf(w[1], sr[1], part);
        part = fmaf(w[2], sr[2], part);
        part = fmaf(w[3], sr[3], part);
    }
    part += __shfl_down(part, 32);
    if (!hi)
        out[(size_t)batch * ODIM + oo] = part + PAIRS * psi_b2[oo];
}

} // namespace

extern "C" void kernel_launch(void* const* d_in, const int* in_sizes, int n_in,
                              void* d_out, int out_size, void* d_ws, size_t ws_size,
                              hipStream_t stream)
{
    const float* x      = (const float*)d_in[0];
    const float* phi_w1 = (const float*)d_in[1];
    const float* phi_b1 = (const float*)d_in[2];
    const float* phi_w2 = (const float*)d_in[3];
    const float* phi_b2 = (const float*)d_in[4];
    const float* psi_w1 = (const float*)d_in[5];
    const float* psi_b1 = (const float*)d_in[6];
    const float* psi_w2 = (const float*)d_in[7];
    const float* psi_b2 = (const float*)d_in[8];

    ushort* Bfrag = (ushort*)d_ws;                       // 16*64*8 ushort = 16 KB
    float* cconst = (float*)((char*)d_ws + 16 * 64 * 8 * sizeof(ushort));
    float* out    = (float*)d_out;

    kan_precompute<<<16, 64, 0, stream>>>(phi_w2, phi_b2, psi_w1, psi_b1, Bfrag, cconst);
    kan_main<<<4096 / 4, 256, 0, stream>>>(x, phi_w1, phi_b1, psi_w2, psi_b2,
                                           Bfrag, cconst, out);
}

// Round 5
// 22.179 us; speedup vs baseline: 2.5283x; 1.0423x over previous
//
#include <hip/hip_runtime.h>

namespace {

typedef float v2f  __attribute__((ext_vector_type(2)));
typedef float v4f  __attribute__((ext_vector_type(4)));
typedef float f32x16 __attribute__((ext_vector_type(16)));
typedef short bf16x8 __attribute__((ext_vector_type(8)));
typedef unsigned short ushort;
typedef unsigned short us8 __attribute__((ext_vector_type(8)));
typedef unsigned int v4u __attribute__((ext_vector_type(4)));
typedef __fp16 h2 __attribute__((ext_vector_type(2)));

constexpr int NDIM = 32;
constexpr int HDIM = 64;
constexpr int ODIM = 32;
constexpr float PAIRS = 496.0f;

// float -> bf16 bits, RTNE (verified in rounds 2-3)
__device__ __forceinline__ ushort f2bf(float f) {
    unsigned int u = __builtin_bit_cast(unsigned int, f);
    u += 0x7fffu + ((u >> 16) & 1u);
    return (ushort)(u >> 16);
}

// ---------------------------------------------------------------------------
// Precompute (coalesced, LDS-staged). Index math equivalent to the verified
// round-3 version:  blockIdx = s*4 + c ;  h = (c&1)*32 + row ; off = (c>>1)*32.
//   Bfrag[(s*4+c)*64 + lane][e] = bf16( W[16s + 8*(lane>>5) + e][32c + (lane&31)] )
//   W[k][hh] = sum_o psi_w1[h, off+o] * phi_w2[o, k]
//   cconst[h] = psi_b1[h] + sum_o (psi_w1[h,o] + psi_w1[h,32+o]) * phi_b2[o]
// ---------------------------------------------------------------------------
__global__ __launch_bounds__(64) void kan_precompute(
    const float* __restrict__ phi_w2, const float* __restrict__ phi_b2,
    const float* __restrict__ psi_w1, const float* __restrict__ psi_b1,
    ushort* __restrict__ Bfrag, float* __restrict__ cconst)
{
    __shared__ float pw2s[32 * 64];   // [o][k], 8 KB
    __shared__ float pw1s[32 * 36];   // [row][o], padded

    const int s = blockIdx.x >> 2, c = blockIdx.x & 3;
    const int lane = threadIdx.x;
    const int hbase = (c & 1) * 32;
    const int off   = (c >> 1) * ODIM;

#pragma unroll
    for (int it = 0; it < 8; ++it) {
        const int idx = it * 256 + lane * 4;
        *(v4f*)&pw2s[idx] = *(const v4f*)(phi_w2 + idx);
    }
#pragma unroll
    for (int it = 0; it < 16; ++it) {
        const int idx = it * 64 + lane;
        const int r = idx >> 5, col = idx & 31;
        pw1s[r * 36 + col] = psi_w1[(hbase + r) * 2 * ODIM + off + col];
    }
    __syncthreads();

    const int row = lane & 31, half = lane >> 5;
    v4f w1r[8];
#pragma unroll
    for (int t = 0; t < 8; ++t) w1r[t] = *(const v4f*)&pw1s[row * 36 + 4 * t];

    us8 out8;
#pragma unroll
    for (int e = 0; e < 8; ++e) {
        const int k = 16 * s + 8 * half + e;
        float m = 0.f;
#pragma unroll
        for (int o = 0; o < 32; ++o)
            m = fmaf(w1r[o >> 2][o & 3], pw2s[o * 64 + k], m);
        out8[e] = f2bf(m);
    }
    *(us8*)(Bfrag + (size_t)(blockIdx.x * 64 + lane) * 8) = out8;

    if (blockIdx.x == 0) {
        float cch = psi_b1[lane];
#pragma unroll
        for (int o = 0; o < ODIM; ++o)
            cch = fmaf(psi_w1[lane * 2 * ODIM + o] + psi_w1[lane * 2 * ODIM + ODIM + o],
                       phi_b2[o], cch);
        cconst[lane] = cch;
    }
}

// ---------------------------------------------------------------------------
// Main: one wave per batch element, 4 waves per block.
// ---------------------------------------------------------------------------
__global__ __launch_bounds__(256, 4) void kan_main(
    const float* __restrict__ x, const float* __restrict__ phi_w1,
    const float* __restrict__ phi_b1, const float* __restrict__ psi_w2,
    const float* __restrict__ psi_b2, const ushort* __restrict__ Bfrag,
    const float* __restrict__ cconst, float* __restrict__ out)
{
    __shared__ v4u  Blds[1024];       // 16 KB staged B-fragments (linear copy)
    __shared__ float sred[4][HDIM];   // 1 KB

    const int tid  = threadIdx.x;
    const int wave = tid >> 6;
    const int lane = tid & 63;
    const int batch = blockIdx.x * 4 + wave;
    const int row  = lane & 31;
    const int half = lane >> 5;
    const bool hi  = lane >= 32;

    // ---- issue Bfrag global loads early (hide latency under stage 1) ----
    const v4u* gB = (const v4u*)Bfrag;
    const v4u t0 = gB[tid];
    const v4u t1 = gB[tid + 256];
    const v4u t2 = gB[tid + 512];
    const v4u t3 = gB[tid + 768];

    const float xn = x[(size_t)batch * NDIM + row];

    // ---- stage 1: h1 directly in A-fragment layout (round-3 verified) --
    bf16x8 afrag[4];
#pragma unroll
    for (int s = 0; s < 4; ++s) {
        const int kb = 16 * s + 8 * half;
        const v4f w1a = *(const v4f*)(phi_w1 + kb);
        const v4f w1b = *(const v4f*)(phi_w1 + kb + 4);
        const v4f b1a = *(const v4f*)(phi_b1 + kb);
        const v4f b1b = *(const v4f*)(phi_b1 + kb + 4);
        bf16x8 t;
#pragma unroll
        for (int e = 0; e < 4; ++e)
            t[e] = (short)f2bf(fmaxf(fmaf(xn, w1a[e], b1a[e]), 0.f));
#pragma unroll
        for (int e = 0; e < 4; ++e)
            t[4 + e] = (short)f2bf(fmaxf(fmaf(xn, w1b[e], b1b[e]), 0.f));
        afrag[s] = t;
    }

    const float cc0 = cconst[row];
    const float cc1 = cconst[32 + row];

    // ---- commit staged B to LDS ----------------------------------------
    Blds[tid]       = t0;
    Blds[tid + 256] = t1;
    Blds[tid + 512] = t2;
    Blds[tid + 768] = t3;
    __syncthreads();

    // ---- stage 2: C = H1 @ W via MFMA, cconst folded into C-init -------
    f32x16 acc0, acc1, acc2, acc3;
#pragma unroll
    for (int r = 0; r < 16; ++r) { acc0[r] = cc0; acc1[r] = cc1; acc2[r] = 0.f; acc3[r] = 0.f; }

    const bf16x8* Bf = (const bf16x8*)Blds;
#pragma unroll
    for (int s = 0; s < 4; ++s) {
        const bf16x8 b0 = Bf[(s * 4 + 0) * 64 + lane];
        const bf16x8 b1 = Bf[(s * 4 + 1) * 64 + lane];
        const bf16x8 b2 = Bf[(s * 4 + 2) * 64 + lane];
        const bf16x8 b3 = Bf[(s * 4 + 3) * 64 + lane];
        acc0 = __builtin_amdgcn_mfma_f32_32x32x16_bf16(afrag[s], b0, acc0, 0, 0, 0);
        acc1 = __builtin_amdgcn_mfma_f32_32x32x16_bf16(afrag[s], b1, acc1, 0, 0, 0);
        acc2 = __builtin_amdgcn_mfma_f32_32x32x16_bf16(afrag[s], b2, acc2, 0, 0, 0);
        acc3 = __builtin_amdgcn_mfma_f32_32x32x16_bf16(afrag[s], b3, acc3, 0, 0, 0);
    }

    // ---- redistribute via __shfl_xor (round-3 verified, verbatim) ------
    v2f Ap0[8], Ap1[8], Bp0[8], Bp1[8];
#pragma unroll
    for (int q = 0; q < 8; ++q) {
        v2f own, snd, oth;
        own.x = hi ? acc1[2 * q]     : acc0[2 * q];
        own.y = hi ? acc1[2 * q + 1] : acc0[2 * q + 1];
        snd.x = hi ? acc0[2 * q]     : acc1[2 * q];
        snd.y = hi ? acc0[2 * q + 1] : acc1[2 * q + 1];
        oth.x = __shfl_xor(snd.x, 32);
        oth.y = __shfl_xor(snd.y, 32);
        Ap0[q].x = hi ? oth.x : own.x;  Ap0[q].y = hi ? oth.y : own.y;
        Ap1[q].x = hi ? own.x : oth.x;  Ap1[q].y = hi ? own.y : oth.y;
    }
#pragma unroll
    for (int q = 0; q < 8; ++q) {
        v2f own, snd, oth;
        own.x = hi ? acc3[2 * q]     : acc2[2 * q];
        own.y = hi ? acc3[2 * q + 1] : acc2[2 * q + 1];
        snd.x = hi ? acc2[2 * q]     : acc3[2 * q];
        snd.y = hi ? acc2[2 * q + 1] : acc3[2 * q + 1];
        oth.x = __shfl_xor(snd.x, 32);
        oth.y = __shfl_xor(snd.y, 32);
        Bp0[q].x = hi ? oth.x : own.x;  Bp0[q].y = hi ? oth.y : own.y;
        Bp1[q].x = hi ? own.x : oth.x;  Bp1[q].y = hi ? own.y : oth.y;
    }

    // ---- unpack to flat Af[n], Bn[n]  (n = nb(2q) {+1, +4, +5}) --------
    float Af[NDIM], Bn[NDIM];
#pragma unroll
    for (int q = 0; q < 8; ++q) {
        const int n0 = ((2 * q) & 3) + 8 * ((2 * q) >> 2);
        Af[n0]     = Ap0[q].x;  Af[n0 + 1] = Ap0[q].y;
        Af[n0 + 4] = Ap1[q].x;  Af[n0 + 5] = Ap1[q].y;
        Bn[n0]     = Bp0[q].x;  Bn[n0 + 1] = Bp0[q].y;
        Bn[n0 + 4] = Bp1[q].x;  Bn[n0 + 5] = Bp1[q].y;
    }

    // ---- stage 3 in packed f16: pk_add + pk_max + v_dot2_f32_f16 -------
    h2 Bh[16];
#pragma unroll
    for (int p = 0; p < 16; ++p)
        Bh[p] = __builtin_amdgcn_cvt_pkrtz(Bn[2 * p], Bn[2 * p + 1]);

    const h2 one2  = {(__fp16)1.f, (__fp16)1.f};
    const h2 zero2 = {(__fp16)0.f, (__fp16)0.f};
    float acc[8] = {0.f, 0.f, 0.f, 0.f, 0.f, 0.f, 0.f, 0.f};

    // boundary pairs (4t,4t+1) and (4t+2,4t+3)
#pragma unroll
    for (int t = 0; t < 8; ++t) {
        const h2 ae = __builtin_amdgcn_cvt_pkrtz(Af[4 * t],     Af[4 * t + 2]);
        const h2 bo = __builtin_amdgcn_cvt_pkrtz(Bn[4 * t + 1], Bn[4 * t + 3]);
        const h2 m  = __builtin_elementwise_max(ae + bo, zero2);
        acc[t] = __builtin_amdgcn_fdot2(m, one2, acc[t], false);
    }
    // main pairs: i vs B-pair p = {2p, 2p+1}, p >= i/2 + 1
#pragma unroll
    for (int i = 0; i < 30; ++i) {
        const h2 ai2 = __builtin_amdgcn_cvt_pkrtz(Af[i], Af[i]);
#pragma unroll
        for (int p = i / 2 + 1; p < 16; ++p) {
            const h2 m = __builtin_elementwise_max(ai2 + Bh[p], zero2);
            acc[p & 7] = __builtin_amdgcn_fdot2(m, one2, acc[p & 7], false);
        }
    }
    const float S = ((acc[0] + acc[1]) + (acc[2] + acc[3])) +
                    ((acc[4] + acc[5]) + (acc[6] + acc[7]));

    sred[wave][lane] = S;   // same-wave DS program order; compiler inserts lgkmcnt

    // ---- epilogue: out[o] = psi_w2[o,:] . S + PAIRS * psi_b2[o] --------
    const int oo = row;
    const float* w2r = psi_w2 + (size_t)oo * HDIM + half * 32;
    float part = 0.f;
#pragma unroll
    for (int r = 0; r < 8; ++r) {
        const v4f w  = *(const v4f*)(w2r + 4 * r);
        const v4f sv = *(const v4f*)&sred[wave][half * 32 + 4 * r];
        part = fmaf(w[0], sv[0], part);
        part = fmaf(w[1], sv[1], part);
        part = fmaf(w[2], sv[2], part);
        part = fmaf(w[3], sv[3], part);
    }
    part += __shfl_down(part, 32);
    if (half == 0)
        out[(size_t)batch * ODIM + oo] = part + PAIRS * psi_b2[oo];
}

} // namespace

extern "C" void kernel_launch(void* const* d_in, const int* in_sizes, int n_in,
                              void* d_out, int out_size, void* d_ws, size_t ws_size,
                              hipStream_t stream)
{
    const float* x      = (const float*)d_in[0];
    const float* phi_w1 = (const float*)d_in[1];
    const float* phi_b1 = (const float*)d_in[2];
    const float* phi_w2 = (const float*)d_in[3];
    const float* phi_b2 = (const float*)d_in[4];
    const float* psi_w1 = (const float*)d_in[5];
    const float* psi_b1 = (const float*)d_in[6];
    const float* psi_w2 = (const float*)d_in[7];
    const float* psi_b2 = (const float*)d_in[8];

    ushort* Bfrag = (ushort*)d_ws;                        // 16*64*8 ushort = 16 KB
    float* cconst = (float*)((char*)d_ws + 16 * 64 * 8 * sizeof(ushort));
    float* out    = (float*)d_out;

    kan_precompute<<<16, 64, 0, stream>>>(phi_w2, phi_b2, psi_w1, psi_b1, Bfrag, cconst);
    kan_main<<<4096 / 4, 256, 0, stream>>>(x, phi_w1, phi_b1, psi_w2, psi_b2,
                                           Bfrag, cconst, out);
}